// Round 3
// baseline (194.318 us; speedup 1.0000x reference)
//
#include <hip/hip_runtime.h>

#define EPSL 1e-9f
#define NGROUPS 638976                    // 8192 * 26 * 3 groups of 31 floats
#define GPW 64                            // groups per wave-tile (1 per lane)
#define TFLOATS (GPW * 31)                // 1984 floats / tensor / tile (7936 B)
#define NTILES (NGROUPS / GPW)            // 9984
#define NBLOCKS 1248                      // 64-thread (1-wave) blocks
#define NT 8                              // NTILES / NBLOCKS exactly, uniform
#define NSLOTS 64

// async 16B global->LDS copy (global_load_lds_dwordx4). LDS dest is the
// wave-uniform base; HW adds lane*16. Source is per-lane.
__device__ __forceinline__ void cp_async16(const float* gsrc, float* ldst) {
    __builtin_amdgcn_global_load_lds(
        (const __attribute__((address_space(1))) void*)(uintptr_t)gsrc,
        (__attribute__((address_space(3))) void*)(uint32_t)(uintptr_t)ldst,
        16, 0, 0);
}

// One wave per block; per-wave private double-buffered LDS pipeline.
// LDS = 31744 B/block -> 5 blocks(waves)/CU; all 1248 blocks co-resident.
// Counted s_waitcnt vmcnt(16) keeps the next tile's 16 loads in flight
// while computing the current tile (no __syncthreads anywhere; block==wave
// so LDS is private and implicitly ordered within the wave).
__global__ __launch_bounds__(64) void laneline_reduce_kernel(
    const float* __restrict__ pred,
    const float* __restrict__ gt,
    float* __restrict__ ws)               // NSLOTS slots of 16 floats
{
    __shared__ float sp[2][TFLOATS];      // pred tiles, 15872 B
    __shared__ float sg[2][TFLOATS];      // gt tiles,   15872 B

    const int lane = threadIdx.x;         // block == one wave

    // stage one 64-group tile into buffer b: exactly 16 async wave-loads
    // (the lane<48 round issues with partial EXEC but still counts once)
    auto stage = [&](int b, int tile) {
        const size_t fb = (size_t)tile * TFLOATS;
        const float* gp = pred + fb + lane * 4;
        const float* gg = gt   + fb + lane * 4;
#pragma unroll
        for (int r = 0; r < 7; ++r) {               // 7 full 1 KB rounds
            cp_async16(gp + r * 256, &sp[b][r * 256]);
            cp_async16(gg + r * 256, &sg[b][r * 256]);
        }
        if (lane < 48) {                            // partial 768 B round
            cp_async16(gp + 1792, &sp[b][1792]);
            cp_async16(gg + 1792, &sg[b][1792]);
        }
    };

    float s0 = 0.f, s1 = 0.f, s2 = 0.f;

    stage(0, blockIdx.x);                 // prologue: tile 0 -> buf 0
#pragma unroll
    for (int it = 0; it < NT; ++it) {
        if (it + 1 < NT) {
            // WAR guard: ensure all prior ds_reads retired before new LDS
            // writes can land in the buffer being restaged; "memory"
            // clobber pins compiler ordering. Cost ~0 (reads already
            // retired via the accumulation dependency chain).
            asm volatile("s_waitcnt lgkmcnt(0)" ::: "memory");
            // issue next tile's 16 loads, then wait ONLY for the current
            // tile's 16 (the oldest): prefetch stays in flight under compute
            stage((it + 1) & 1, blockIdx.x + (it + 1) * NBLOCKS);
            asm volatile("s_waitcnt vmcnt(16)" ::: "memory");
        } else {
            asm volatile("s_waitcnt vmcnt(0)" ::: "memory");
        }

        // one 31-dim group per lane; LDS stride 31 (odd) -> 2 lanes/bank, free
        const float* lp = &sp[it & 1][lane * 31];
        const float* lg = &sg[it & 1][lane * 31];

        const float gcls = lg[30];
#pragma unroll
        for (int i = 0; i < 10; ++i) {
            const float gvis = lg[20 + i];
            // gt ~ U[0,1): gcls*gvis >= 0 so |w*(p-g)| = w*|p-g|
            s2 += gcls * gvis * (fabsf(lp[i]      - lg[i])
                               + fabsf(lp[10 + i] - lg[10 + i]));
            const float pv = lp[20 + i];
            s0 += gvis * __logf(pv + EPSL)
                + (1.0f - gvis + EPSL) * __logf(1.0f - pv + EPSL);
        }
        const float pc = lp[30];
        s1 += gcls * __logf(pc + EPSL)
            + (1.0f - gcls) * __logf(1.0f - pc + EPSL);
    }

    // ---- wave shuffle reduction, one atomic triple per wave ----
#pragma unroll
    for (int off = 32; off > 0; off >>= 1) {
        s0 += __shfl_down(s0, off, 64);
        s1 += __shfl_down(s1, off, 64);
        s2 += __shfl_down(s2, off, 64);
    }
    if (lane == 0) {
        float* slot = ws + (blockIdx.x & (NSLOTS - 1)) * 16;  // 64 B stride
        atomicAdd(&slot[0], s0);
        atomicAdd(&slot[1], s1);
        atomicAdd(&slot[2], s2);
    }
}

__global__ __launch_bounds__(64) void laneline_finalize_kernel(
    const float* __restrict__ ws, float* __restrict__ out)
{
    const int t = threadIdx.x;
    float v0 = ws[t * 16], v1 = ws[t * 16 + 1], v2 = ws[t * 16 + 2];
#pragma unroll
    for (int off = 32; off > 0; off >>= 1) {
        v0 += __shfl_down(v0, off, 64);
        v1 += __shfl_down(v1, off, 64);
        v2 += __shfl_down(v2, off, 64);
    }
    if (t == 0) {
        const float l0 = -v0 * 0.1f;   // / NUM_Y_STEPS, negated
        const float l1 = -v1;
        const float l2 =  v2;
        out[0] = l0 + l1 + l2;
        out[1] = l0;
        out[2] = l1;
        out[3] = l2;
    }
}

extern "C" void kernel_launch(void* const* d_in, const int* in_sizes, int n_in,
                              void* d_out, int out_size, void* d_ws, size_t ws_size,
                              hipStream_t stream)
{
    const float* pred = (const float*)d_in[0];
    const float* gt   = (const float*)d_in[1];
    // d_in[2..5] (hcam/pitch) are unused by the reference computation.
    float* ws  = (float*)d_ws;
    float* out = (float*)d_out;

    hipMemsetAsync(ws, 0, NSLOTS * 16 * sizeof(float), stream);

    laneline_reduce_kernel<<<NBLOCKS, 64, 0, stream>>>(pred, gt, ws);
    laneline_finalize_kernel<<<1, 64, 0, stream>>>(ws, out);
}